// Round 7
// baseline (290.511 us; speedup 1.0000x reference)
//
#include <hip/hip_runtime.h>

#define N_NODES 100000
#define N_EDGES 1600000
#define HID 128
#define N_GRAPHS 256
#define POOL_BLOCKS 512

#define BSHIFT 9
#define BSIZE 512
#define NBUCK ((N_NODES + BSIZE - 1) / BSIZE)   // 196
#define BCAP 10240                               // >> mean 8192 + 22 sigma
#define EPB 8192
#define NBLK_A ((N_EDGES + EPB - 1) / EPB)      // 196

typedef unsigned int uint;
typedef unsigned short ushort;
typedef short short8 __attribute__((ext_vector_type(8)));
typedef float f32x4 __attribute__((ext_vector_type(4)));

__device__ __forceinline__ float bf2f(ushort u) {
    return __uint_as_float(((uint)u) << 16);
}
__device__ __forceinline__ ushort f2bf(float f) {
    uint u = __float_as_uint(f);
    u += 0x7FFFu + ((u >> 16) & 1u);   // round-to-nearest-even
    return (ushort)(u >> 16);
}
__device__ __forceinline__ uint4 pack8(const float* r) {
    uint4 o;
    o.x = (uint)f2bf(r[0]) | ((uint)f2bf(r[1]) << 16);
    o.y = (uint)f2bf(r[2]) | ((uint)f2bf(r[3]) << 16);
    o.z = (uint)f2bf(r[4]) | ((uint)f2bf(r[5]) << 16);
    o.w = (uint)f2bf(r[6]) | ((uint)f2bf(r[7]) << 16);
    return o;
}
// accumulate 8 bf16 (packed uint4) into 4 float2 (paired for v_pk_add_f32)
__device__ __forceinline__ void accp(uint4 v, float2* a) {
    a[0].x += __uint_as_float(v.x << 16);
    a[0].y += __uint_as_float(v.x & 0xFFFF0000u);
    a[1].x += __uint_as_float(v.y << 16);
    a[1].y += __uint_as_float(v.y & 0xFFFF0000u);
    a[2].x += __uint_as_float(v.z << 16);
    a[2].y += __uint_as_float(v.z & 0xFFFF0000u);
    a[3].x += __uint_as_float(v.w << 16);
    a[3].y += __uint_as_float(v.w & 0xFFFF0000u);
}

union Frag16 {
    uint4 u;
    short8 s;
    ushort h[8];
};

// ---------------- zero ----------------
__global__ void zero_kernel(int* __restrict__ p, int n) {
    int i = blockIdx.x * blockDim.x + threadIdx.x;
    if (i < n) p[i] = 0;
}

// ---------------- bucketed CSR build (fixed-capacity buckets, single scatter pass) ----------------
__global__ __launch_bounds__(256) void bucket_scatter_kernel(const int* __restrict__ src,
                                                             const int* __restrict__ dst,
                                                             int* __restrict__ bfill,
                                                             uint* __restrict__ bucketed) {
    __shared__ int h[NBUCK];
    __shared__ int rb[NBUCK];
    for (int t = threadIdx.x; t < NBUCK; t += 256) h[t] = 0;
    __syncthreads();
    int base = blockIdx.x * EPB;
#pragma unroll 4
    for (int it = 0; it < EPB / 256; ++it) {
        int e = base + it * 256 + threadIdx.x;
        if (e < N_EDGES) atomicAdd(&h[dst[e] >> BSHIFT], 1);
    }
    __syncthreads();
    for (int t = threadIdx.x; t < NBUCK; t += 256) {
        rb[t] = (h[t] ? atomicAdd(&bfill[t], h[t]) : 0) + t * BCAP;
        h[t] = 0;
    }
    __syncthreads();
#pragma unroll 4
    for (int it = 0; it < EPB / 256; ++it) {
        int e = base + it * 256 + threadIdx.x;
        if (e < N_EDGES) {
            int d = dst[e];
            int b = d >> BSHIFT;
            int pos = rb[b] + atomicAdd(&h[b], 1);
            bucketed[pos] = (uint)src[e] | ((uint)(d & (BSIZE - 1)) << 17);
        }
    }
}

// one block per bucket -> local count/scan/scatter; csr holds BYTE offsets (src*256)
__global__ __launch_bounds__(256) void bucket_csr_kernel(const uint* __restrict__ bucketed,
                                                         const int* __restrict__ bfill,
                                                         int* __restrict__ degi,
                                                         int* __restrict__ rowptr,
                                                         float* __restrict__ dis,
                                                         uint* __restrict__ csrb) {
    int b = blockIdx.x;
    int beg = b * BCAP;
    int ne = bfill[b];
    __shared__ int cnt[BSIZE];
    __shared__ int fl[BSIZE];
    __shared__ int ex[BSIZE];
    __shared__ int ps[256];
    int t = threadIdx.x;
    cnt[t] = 0; cnt[t + 256] = 0;
    fl[t] = 0;  fl[t + 256] = 0;
    __syncthreads();
    for (int i = t; i < ne; i += 256) atomicAdd(&cnt[bucketed[beg + i] >> 17], 1);
    __syncthreads();
    int v0 = cnt[2 * t], v1 = cnt[2 * t + 1];
    int s = v0 + v1;
    ps[t] = s;
    __syncthreads();
    for (int off = 1; off < 256; off <<= 1) {
        int a = (t >= off) ? ps[t - off] : 0;
        __syncthreads();
        ps[t] += a;
        __syncthreads();
    }
    int e0 = ps[t] - s;
    ex[2 * t] = e0;
    ex[2 * t + 1] = e0 + v0;
    int g = b * BSIZE + 2 * t;
    if (g < N_NODES) {
        degi[g] = v0; rowptr[g] = beg + e0;
        dis[g] = rsqrtf(1.0f + (float)v0);
    }
    if (g + 1 < N_NODES) {
        degi[g + 1] = v1; rowptr[g + 1] = beg + e0 + v0;
        dis[g + 1] = rsqrtf(1.0f + (float)v1);
    }
    __syncthreads();
    for (int i = t; i < ne; i += 256) {
        uint u = bucketed[beg + i];
        int dl = u >> 17;
        int p = ex[dl] + atomicAdd(&fl[dl], 1);
        csrb[beg + p] = (u & 0x1FFFFu) << 8;   // byte offset: src * 256
    }
}

// ---------------- W -> B-fragment pre-pack (both layers in one launch) ----------------
__global__ void prep_wfrag2(const float* __restrict__ W1, const float* __restrict__ W2,
                            uint4* __restrict__ WB1, uint4* __restrict__ WB2) {
    int t = blockIdx.x * 256 + threadIdx.x;
    if (t >= 4096) return;
    const float* W = (t < 2048) ? W1 : W2;
    uint4* WB = (t < 2048) ? WB1 : WB2;
    int tt = t & 2047;
    int lane = tt & 63;
    int nt = (tt >> 6) & 7;
    int kt = tt >> 9;
    int kbase = kt * 32 + (lane >> 4) * 8;
    int col = nt * 16 + (lane & 15);
    float r[8];
#pragma unroll
    for (int j = 0; j < 8; j++) r[j] = W[(size_t)(kbase + j) * 128 + col];
    WB[tt] = pack8(r);
}

// ---------------- MFMA GEMM: Y_bf16[M,128] = (X[M,128] @ W) * dis[row] ----------------
template <bool F32IN>
__global__ __launch_bounds__(256) void mgemm_kernel(const void* __restrict__ Xv,
                                                    const uint4* __restrict__ WB,
                                                    const float* __restrict__ dis,
                                                    ushort* __restrict__ Y, int M) {
    __shared__ uint4 WBs[2048];
#pragma unroll
    for (int i = 0; i < 8; i++) WBs[i * 256 + threadIdx.x] = WB[i * 256 + threadIdx.x];
    __syncthreads();

    int wave = threadIdx.x >> 6;
    int lane = threadIdx.x & 63;
    int r0 = blockIdx.x * 128 + wave * 32;
    if (r0 >= M) return;

    int rowA = lane & 15;
    int ksub = (lane >> 4) * 8;

    Frag16 a[2][4];
#pragma unroll
    for (int rt = 0; rt < 2; ++rt) {
        int row = r0 + rt * 16 + rowA;
        if (F32IN) {
            const float* xr = (const float*)Xv + (size_t)row * 128;
#pragma unroll
            for (int kt = 0; kt < 4; ++kt) {
                float4 lo = *(const float4*)(xr + kt * 32 + ksub);
                float4 hi = *(const float4*)(xr + kt * 32 + ksub + 4);
                float r[8] = {lo.x, lo.y, lo.z, lo.w, hi.x, hi.y, hi.z, hi.w};
                a[rt][kt].u = pack8(r);
            }
        } else {
            const uint4* xr = (const uint4*)Xv + (size_t)row * 16;
#pragma unroll
            for (int kt = 0; kt < 4; ++kt) a[rt][kt].u = xr[kt * 4 + (lane >> 4)];
        }
    }

    f32x4 acc[2][8];
#pragma unroll
    for (int rt = 0; rt < 2; ++rt)
#pragma unroll
        for (int nt = 0; nt < 8; ++nt) acc[rt][nt] = (f32x4){0.f, 0.f, 0.f, 0.f};

#pragma unroll
    for (int kt = 0; kt < 4; ++kt) {
#pragma unroll
        for (int nt = 0; nt < 8; ++nt) {
            Frag16 b;
            b.u = WBs[(kt * 8 + nt) * 64 + lane];
            acc[0][nt] = __builtin_amdgcn_mfma_f32_16x16x32_bf16(a[0][kt].s, b.s, acc[0][nt], 0, 0, 0);
            acc[1][nt] = __builtin_amdgcn_mfma_f32_16x16x32_bf16(a[1][kt].s, b.s, acc[1][nt], 0, 0, 0);
        }
    }

    int cbase = lane & 15;
#pragma unroll
    for (int rt = 0; rt < 2; ++rt) {
        int rbase = r0 + rt * 16 + (lane >> 4) * 4;
        float d0 = dis[rbase + 0], d1 = dis[rbase + 1];
        float d2 = dis[rbase + 2], d3 = dis[rbase + 3];
#pragma unroll
        for (int nt = 0; nt < 8; ++nt) {
            Y[(size_t)(rbase + 0) * 128 + nt * 16 + cbase] = f2bf(acc[rt][nt][0] * d0);
            Y[(size_t)(rbase + 1) * 128 + nt * 16 + cbase] = f2bf(acc[rt][nt][1] * d1);
            Y[(size_t)(rbase + 2) * 128 + nt * 16 + cbase] = f2bf(acc[rt][nt][2] * d2);
            Y[(size_t)(rbase + 3) * 128 + nt * 16 + cbase] = f2bf(acc[rt][nt][3] * d3);
        }
    }
}

// ---------------- aggregation ----------------
// T holds T' = (X@W)*dis[src] in bf16 rows of 256B. csrb holds BYTE offsets.
// agg[dst] = relu(dis[dst]*(sum T'[nbr] + T'[dst]) + b). Quarter-wave per row, 8 in flight.
__global__ __launch_bounds__(256) void aggregate_kernel(
    const ushort* __restrict__ T, const uint* __restrict__ csrb,
    const int* __restrict__ rowptr, const int* __restrict__ degi,
    const float* __restrict__ dis, const float* __restrict__ bias,
    ushort* __restrict__ H) {
    int node = blockIdx.x * 4 + (threadIdx.x >> 6);
    int lane = threadIdx.x & 63;
    if (node >= N_NODES) return;
    int group = lane >> 4;
    uint sub16 = (uint)(lane & 15) * 16u;   // byte offset within row

    int start = rowptr[node];
    int cnt = degi[node];
    const char* Tb = (const char*)T;

    float2 acc[4];
#pragma unroll
    for (int i = 0; i < 4; i++) acc[i] = make_float2(0.f, 0.f);

    int j = group;
    for (; j + 28 < cnt; j += 32) {
        uint o0 = csrb[start + j];
        uint o1 = csrb[start + j + 4];
        uint o2 = csrb[start + j + 8];
        uint o3 = csrb[start + j + 12];
        uint o4 = csrb[start + j + 16];
        uint o5 = csrb[start + j + 20];
        uint o6 = csrb[start + j + 24];
        uint o7 = csrb[start + j + 28];
        uint4 v0 = *(const uint4*)(Tb + (o0 + sub16));
        uint4 v1 = *(const uint4*)(Tb + (o1 + sub16));
        uint4 v2 = *(const uint4*)(Tb + (o2 + sub16));
        uint4 v3 = *(const uint4*)(Tb + (o3 + sub16));
        uint4 v4 = *(const uint4*)(Tb + (o4 + sub16));
        uint4 v5 = *(const uint4*)(Tb + (o5 + sub16));
        uint4 v6 = *(const uint4*)(Tb + (o6 + sub16));
        uint4 v7 = *(const uint4*)(Tb + (o7 + sub16));
        accp(v0, acc); accp(v1, acc); accp(v2, acc); accp(v3, acc);
        accp(v4, acc); accp(v5, acc); accp(v6, acc); accp(v7, acc);
    }
    for (; j + 12 < cnt; j += 16) {
        uint o0 = csrb[start + j];
        uint o1 = csrb[start + j + 4];
        uint o2 = csrb[start + j + 8];
        uint o3 = csrb[start + j + 12];
        uint4 v0 = *(const uint4*)(Tb + (o0 + sub16));
        uint4 v1 = *(const uint4*)(Tb + (o1 + sub16));
        uint4 v2 = *(const uint4*)(Tb + (o2 + sub16));
        uint4 v3 = *(const uint4*)(Tb + (o3 + sub16));
        accp(v0, acc); accp(v1, acc); accp(v2, acc); accp(v3, acc);
    }
    for (; j < cnt; j += 4) {
        uint o0 = csrb[start + j];
        uint4 v0 = *(const uint4*)(Tb + (o0 + sub16));
        accp(v0, acc);
    }

#pragma unroll
    for (int i = 0; i < 4; i++) {
        acc[i].x += __shfl_xor(acc[i].x, 16);
        acc[i].y += __shfl_xor(acc[i].y, 16);
        acc[i].x += __shfl_xor(acc[i].x, 32);
        acc[i].y += __shfl_xor(acc[i].y, 32);
    }

    if (group == 0) {
        // self term (weight 1), then scale by dis[node], bias, relu
        uint4 sv = *(const uint4*)(Tb + (((uint)node << 8) + sub16));
        accp(sv, acc);
        float di = dis[node];
        int sub = lane & 15;
        float4 blo = ((const float4*)bias)[sub * 2];
        float4 bhi = ((const float4*)bias)[sub * 2 + 1];
        float bb[8] = {blo.x, blo.y, blo.z, blo.w, bhi.x, bhi.y, bhi.z, bhi.w};
        float r[8];
        float af[8] = {acc[0].x, acc[0].y, acc[1].x, acc[1].y,
                       acc[2].x, acc[2].y, acc[3].x, acc[3].y};
#pragma unroll
        for (int i = 0; i < 8; i++) r[i] = fmaxf(di * af[i] + bb[i], 0.f);
        ((uint4*)H)[(size_t)node * 16 + sub] = pack8(r);
    }
}

// ---------------- pool: chunked per-wave run-accumulation over sorted batch ----------------
__global__ __launch_bounds__(256) void pool_kernel(const ushort* __restrict__ H,
                                                   const int* __restrict__ batch,
                                                   const float* __restrict__ Wfc,
                                                   float* __restrict__ gsum) {
    int wave = threadIdx.x >> 6;
    int lane = threadIdx.x & 63;
    int wid = blockIdx.x * 4 + wave;
    const int nwaves = POOL_BLOCKS * 4;
    const int per = (N_NODES + nwaves - 1) / nwaves;
    int start = wid * per;
    int end = min(start + per, N_NODES);
    if (start >= end) return;

    const uint* H1 = (const uint*)H;
    float2 w = ((const float2*)Wfc)[lane];
    float2 acc = make_float2(0.f, 0.f);
    int gcur = batch[start];

    for (int node = start; node < end; ++node) {
        int g = batch[node];
        if (g != gcur) {
            float d = acc.x * w.x + acc.y * w.y;
#pragma unroll
            for (int off = 32; off > 0; off >>= 1) d += __shfl_down(d, off);
            if (lane == 0) atomicAdd(&gsum[gcur], d);
            acc = make_float2(0.f, 0.f);
            gcur = g;
        }
        uint v = H1[(size_t)node * 64 + lane];
        acc.x += bf2f((ushort)(v & 0xFFFF));
        acc.y += bf2f((ushort)(v >> 16));
    }
    float d = acc.x * w.x + acc.y * w.y;
#pragma unroll
    for (int off = 32; off > 0; off >>= 1) d += __shfl_down(d, off);
    if (lane == 0) atomicAdd(&gsum[gcur], d);
}

// ---------------- finalize ----------------
__global__ void finalize_kernel(const float* __restrict__ gsum, const int* __restrict__ batch,
                                const float* __restrict__ bfc, float* __restrict__ out) {
    int g = threadIdx.x;
    if (g >= N_GRAPHS) return;
    auto lb = [&](int key) {
        int lo = 0, hi = N_NODES;
        while (lo < hi) {
            int mid = (lo + hi) >> 1;
            if (batch[mid] < key) lo = mid + 1; else hi = mid;
        }
        return lo;
    };
    int a = lb(g), b = lb(g + 1);
    float cnt = (float)(b - a);
    out[g] = gsum[g] / fmaxf(cnt, 1.0f) + bfc[0];
}

// ---------------- launcher ----------------
extern "C" void kernel_launch(void* const* d_in, const int* in_sizes, int n_in,
                              void* d_out, int out_size, void* d_ws, size_t ws_size,
                              hipStream_t stream) {
    const float* x    = (const float*)d_in[0];
    const int*   eidx = (const int*)d_in[1];
    const int*   batch= (const int*)d_in[2];
    const float* W1   = (const float*)d_in[3];
    const float* b1   = (const float*)d_in[4];
    const float* W2   = (const float*)d_in[5];
    const float* b2   = (const float*)d_in[6];
    const float* Wfc  = (const float*)d_in[7];
    const float* bfc  = (const float*)d_in[8];
    float* out = (float*)d_out;

    const int* src = eidx;
    const int* dst = eidx + N_EDGES;

    size_t off = 0;
    char* base = (char*)d_ws;
    auto alloc = [&](size_t bytes) -> void* {
        void* p = base + off;
        off += (bytes + 255) & ~(size_t)255;
        return p;
    };
    // zeroed region first: bfill, gsum
    int*    bfill  = (int*)alloc(NBUCK * 4);
    float*  gsum   = (float*)alloc(N_GRAPHS * 4);
    size_t zero_bytes = off;
    ushort* A      = (ushort*)alloc((size_t)N_NODES * HID * 2);
    ushort* B      = (ushort*)alloc((size_t)N_NODES * HID * 2);
    int*    degi   = (int*)alloc(N_NODES * 4);
    int*    rowptr = (int*)alloc(N_NODES * 4);
    float*  dis    = (float*)alloc(N_NODES * 4);
    uint*   csrb   = (uint*)alloc((size_t)NBUCK * BCAP * 4);
    uint*   bucketed = (uint*)alloc((size_t)NBUCK * BCAP * 4);
    uint4*  WB1    = (uint4*)alloc(2048 * 16);
    uint4*  WB2    = (uint4*)alloc(2048 * 16);

    int zn = (int)(zero_bytes / 4);
    zero_kernel<<<(zn + 255) / 256, 256, 0, stream>>>((int*)base, zn);

    // bucketed CSR build (fixed-capacity, 2 passes total)
    bucket_scatter_kernel<<<NBLK_A, 256, 0, stream>>>(src, dst, bfill, bucketed);
    bucket_csr_kernel<<<NBUCK, 256, 0, stream>>>(bucketed, bfill, degi, rowptr, dis, csrb);

    // W fragment pre-pack (both layers)
    prep_wfrag2<<<16, 256, 0, stream>>>(W1, W2, WB1, WB2);

    int gemm_grid = (N_NODES + 127) / 128;
    int agg_grid  = (N_NODES + 3) / 4;

    // layer 1
    mgemm_kernel<true><<<gemm_grid, 256, 0, stream>>>(x, WB1, dis, A, N_NODES);
    aggregate_kernel<<<agg_grid, 256, 0, stream>>>(A, csrb, rowptr, degi, dis, b1, B);
    // layer 2
    mgemm_kernel<false><<<gemm_grid, 256, 0, stream>>>(B, WB2, dis, A, N_NODES);
    aggregate_kernel<<<agg_grid, 256, 0, stream>>>(A, csrb, rowptr, degi, dis, b2, B);

    // pool + fc
    pool_kernel<<<POOL_BLOCKS, 256, 0, stream>>>(B, batch, Wfc, gsum);
    finalize_kernel<<<1, 256, 0, stream>>>(gsum, batch, bfc, out);
}

// Round 8
// 254.009 us; speedup vs baseline: 1.1437x; 1.1437x over previous
//
#include <hip/hip_runtime.h>

#define N_NODES 100000
#define N_EDGES 1600000
#define HID 128
#define N_GRAPHS 256
#define POOL_BLOCKS 512

#define BSHIFT 9
#define BSIZE 512
#define NBUCK ((N_NODES + BSIZE - 1) / BSIZE)   // 196
#define BCAP 10240                               // >> mean 8192 + 22 sigma
#define EPB 8192
#define NBLK_A ((N_EDGES + EPB - 1) / EPB)      // 196

typedef unsigned int uint;
typedef unsigned short ushort;
typedef short short8 __attribute__((ext_vector_type(8)));
typedef float f32x4 __attribute__((ext_vector_type(4)));

__device__ __forceinline__ float bf2f(ushort u) {
    return __uint_as_float(((uint)u) << 16);
}
__device__ __forceinline__ ushort f2bf(float f) {
    uint u = __float_as_uint(f);
    u += 0x7FFFu + ((u >> 16) & 1u);   // round-to-nearest-even
    return (ushort)(u >> 16);
}
__device__ __forceinline__ uint4 pack8(const float* r) {
    uint4 o;
    o.x = (uint)f2bf(r[0]) | ((uint)f2bf(r[1]) << 16);
    o.y = (uint)f2bf(r[2]) | ((uint)f2bf(r[3]) << 16);
    o.z = (uint)f2bf(r[4]) | ((uint)f2bf(r[5]) << 16);
    o.w = (uint)f2bf(r[6]) | ((uint)f2bf(r[7]) << 16);
    return o;
}
// accumulate 8 bf16 (packed uint4) into 4 float2 (paired for v_pk_add_f32)
__device__ __forceinline__ void accp(uint4 v, float2* a) {
    a[0].x += __uint_as_float(v.x << 16);
    a[0].y += __uint_as_float(v.x & 0xFFFF0000u);
    a[1].x += __uint_as_float(v.y << 16);
    a[1].y += __uint_as_float(v.y & 0xFFFF0000u);
    a[2].x += __uint_as_float(v.z << 16);
    a[2].y += __uint_as_float(v.z & 0xFFFF0000u);
    a[3].x += __uint_as_float(v.w << 16);
    a[3].y += __uint_as_float(v.w & 0xFFFF0000u);
}

union Frag16 {
    uint4 u;
    short8 s;
    ushort h[8];
};

// ---------------- zero ----------------
__global__ void zero_kernel(int* __restrict__ p, int n) {
    int i = blockIdx.x * blockDim.x + threadIdx.x;
    if (i < n) p[i] = 0;
}

// ---------------- bucketed CSR build (fixed-capacity buckets, single scatter pass) ----------------
__global__ __launch_bounds__(256) void bucket_scatter_kernel(const int* __restrict__ src,
                                                             const int* __restrict__ dst,
                                                             int* __restrict__ bfill,
                                                             uint* __restrict__ bucketed) {
    __shared__ int h[NBUCK];
    __shared__ int rb[NBUCK];
    for (int t = threadIdx.x; t < NBUCK; t += 256) h[t] = 0;
    __syncthreads();
    int base = blockIdx.x * EPB;
#pragma unroll 4
    for (int it = 0; it < EPB / 256; ++it) {
        int e = base + it * 256 + threadIdx.x;
        if (e < N_EDGES) atomicAdd(&h[dst[e] >> BSHIFT], 1);
    }
    __syncthreads();
    for (int t = threadIdx.x; t < NBUCK; t += 256) {
        rb[t] = (h[t] ? atomicAdd(&bfill[t], h[t]) : 0) + t * BCAP;
        h[t] = 0;
    }
    __syncthreads();
#pragma unroll 4
    for (int it = 0; it < EPB / 256; ++it) {
        int e = base + it * 256 + threadIdx.x;
        if (e < N_EDGES) {
            int d = dst[e];
            int b = d >> BSHIFT;
            int pos = rb[b] + atomicAdd(&h[b], 1);
            bucketed[pos] = (uint)src[e] | ((uint)(d & (BSIZE - 1)) << 17);
        }
    }
}

// one block per bucket -> local count/scan/scatter; csr holds BYTE offsets (src*256)
__global__ __launch_bounds__(256) void bucket_csr_kernel(const uint* __restrict__ bucketed,
                                                         const int* __restrict__ bfill,
                                                         int* __restrict__ degi,
                                                         int* __restrict__ rowptr,
                                                         float* __restrict__ dis,
                                                         uint* __restrict__ csrb) {
    int b = blockIdx.x;
    int beg = b * BCAP;
    int ne = bfill[b];
    __shared__ int cnt[BSIZE];
    __shared__ int fl[BSIZE];
    __shared__ int ex[BSIZE];
    __shared__ int ps[256];
    int t = threadIdx.x;
    cnt[t] = 0; cnt[t + 256] = 0;
    fl[t] = 0;  fl[t + 256] = 0;
    __syncthreads();
    for (int i = t; i < ne; i += 256) atomicAdd(&cnt[bucketed[beg + i] >> 17], 1);
    __syncthreads();
    int v0 = cnt[2 * t], v1 = cnt[2 * t + 1];
    int s = v0 + v1;
    ps[t] = s;
    __syncthreads();
    for (int off = 1; off < 256; off <<= 1) {
        int a = (t >= off) ? ps[t - off] : 0;
        __syncthreads();
        ps[t] += a;
        __syncthreads();
    }
    int e0 = ps[t] - s;
    ex[2 * t] = e0;
    ex[2 * t + 1] = e0 + v0;
    int g = b * BSIZE + 2 * t;
    if (g < N_NODES) {
        degi[g] = v0; rowptr[g] = beg + e0;
        dis[g] = rsqrtf(1.0f + (float)v0);
    }
    if (g + 1 < N_NODES) {
        degi[g + 1] = v1; rowptr[g + 1] = beg + e0 + v0;
        dis[g + 1] = rsqrtf(1.0f + (float)v1);
    }
    __syncthreads();
    for (int i = t; i < ne; i += 256) {
        uint u = bucketed[beg + i];
        int dl = u >> 17;
        int p = ex[dl] + atomicAdd(&fl[dl], 1);
        csrb[beg + p] = (u & 0x1FFFFu) << 8;   // byte offset: src * 256
    }
}

// ---------------- W -> B-fragment pre-pack (both layers in one launch) ----------------
__global__ void prep_wfrag2(const float* __restrict__ W1, const float* __restrict__ W2,
                            uint4* __restrict__ WB1, uint4* __restrict__ WB2) {
    int t = blockIdx.x * 256 + threadIdx.x;
    if (t >= 4096) return;
    const float* W = (t < 2048) ? W1 : W2;
    uint4* WB = (t < 2048) ? WB1 : WB2;
    int tt = t & 2047;
    int lane = tt & 63;
    int nt = (tt >> 6) & 7;
    int kt = tt >> 9;
    int kbase = kt * 32 + (lane >> 4) * 8;
    int col = nt * 16 + (lane & 15);
    float r[8];
#pragma unroll
    for (int j = 0; j < 8; j++) r[j] = W[(size_t)(kbase + j) * 128 + col];
    WB[tt] = pack8(r);
}

// ---------------- MFMA GEMM: Y_bf16[M,128] = (X[M,128] @ W) * dis[row] ----------------
template <bool F32IN>
__global__ __launch_bounds__(256) void mgemm_kernel(const void* __restrict__ Xv,
                                                    const uint4* __restrict__ WB,
                                                    const float* __restrict__ dis,
                                                    ushort* __restrict__ Y, int M) {
    __shared__ uint4 WBs[2048];
#pragma unroll
    for (int i = 0; i < 8; i++) WBs[i * 256 + threadIdx.x] = WB[i * 256 + threadIdx.x];
    __syncthreads();

    int wave = threadIdx.x >> 6;
    int lane = threadIdx.x & 63;
    int r0 = blockIdx.x * 128 + wave * 32;
    if (r0 >= M) return;

    int rowA = lane & 15;
    int ksub = (lane >> 4) * 8;

    Frag16 a[2][4];
#pragma unroll
    for (int rt = 0; rt < 2; ++rt) {
        int row = r0 + rt * 16 + rowA;
        if (F32IN) {
            const float* xr = (const float*)Xv + (size_t)row * 128;
#pragma unroll
            for (int kt = 0; kt < 4; ++kt) {
                float4 lo = *(const float4*)(xr + kt * 32 + ksub);
                float4 hi = *(const float4*)(xr + kt * 32 + ksub + 4);
                float r[8] = {lo.x, lo.y, lo.z, lo.w, hi.x, hi.y, hi.z, hi.w};
                a[rt][kt].u = pack8(r);
            }
        } else {
            const uint4* xr = (const uint4*)Xv + (size_t)row * 16;
#pragma unroll
            for (int kt = 0; kt < 4; ++kt) a[rt][kt].u = xr[kt * 4 + (lane >> 4)];
        }
    }

    f32x4 acc[2][8];
#pragma unroll
    for (int rt = 0; rt < 2; ++rt)
#pragma unroll
        for (int nt = 0; nt < 8; ++nt) acc[rt][nt] = (f32x4){0.f, 0.f, 0.f, 0.f};

#pragma unroll
    for (int kt = 0; kt < 4; ++kt) {
#pragma unroll
        for (int nt = 0; nt < 8; ++nt) {
            Frag16 b;
            b.u = WBs[(kt * 8 + nt) * 64 + lane];
            acc[0][nt] = __builtin_amdgcn_mfma_f32_16x16x32_bf16(a[0][kt].s, b.s, acc[0][nt], 0, 0, 0);
            acc[1][nt] = __builtin_amdgcn_mfma_f32_16x16x32_bf16(a[1][kt].s, b.s, acc[1][nt], 0, 0, 0);
        }
    }

    int cbase = lane & 15;
#pragma unroll
    for (int rt = 0; rt < 2; ++rt) {
        int rbase = r0 + rt * 16 + (lane >> 4) * 4;
        float d0 = dis[rbase + 0], d1 = dis[rbase + 1];
        float d2 = dis[rbase + 2], d3 = dis[rbase + 3];
#pragma unroll
        for (int nt = 0; nt < 8; ++nt) {
            Y[(size_t)(rbase + 0) * 128 + nt * 16 + cbase] = f2bf(acc[rt][nt][0] * d0);
            Y[(size_t)(rbase + 1) * 128 + nt * 16 + cbase] = f2bf(acc[rt][nt][1] * d1);
            Y[(size_t)(rbase + 2) * 128 + nt * 16 + cbase] = f2bf(acc[rt][nt][2] * d2);
            Y[(size_t)(rbase + 3) * 128 + nt * 16 + cbase] = f2bf(acc[rt][nt][3] * d3);
        }
    }
}

// ---------------- aggregation ----------------
// T holds T' = (X@W)*dis[src] in bf16 rows of 256B. csrb holds BYTE offsets.
// agg[dst] = relu(dis[dst]*(sum T'[nbr] + T'[dst]) + b).
// One wave per node, quarter-wave per row, 4 gathers in flight (R6-proven shape).
__global__ __launch_bounds__(256) void aggregate_kernel(
    const ushort* __restrict__ T, const uint* __restrict__ csrb,
    const int* __restrict__ rowptr, const int* __restrict__ degi,
    const float* __restrict__ dis, const float* __restrict__ bias,
    ushort* __restrict__ H) {
    int node = blockIdx.x * 4 + (threadIdx.x >> 6);
    int lane = threadIdx.x & 63;
    if (node >= N_NODES) return;
    int group = lane >> 4;
    uint sub16 = (uint)(lane & 15) * 16u;   // byte offset within row

    int start = rowptr[node];
    int cnt = degi[node];
    const char* Tb = (const char*)T;

    float2 acc[4];
#pragma unroll
    for (int i = 0; i < 4; i++) acc[i] = make_float2(0.f, 0.f);

    int j = group;
    for (; j + 12 < cnt; j += 16) {
        uint o0 = csrb[start + j];
        uint o1 = csrb[start + j + 4];
        uint o2 = csrb[start + j + 8];
        uint o3 = csrb[start + j + 12];
        uint4 v0 = *(const uint4*)(Tb + (o0 + sub16));
        uint4 v1 = *(const uint4*)(Tb + (o1 + sub16));
        uint4 v2 = *(const uint4*)(Tb + (o2 + sub16));
        uint4 v3 = *(const uint4*)(Tb + (o3 + sub16));
        accp(v0, acc); accp(v1, acc); accp(v2, acc); accp(v3, acc);
    }
    for (; j < cnt; j += 4) {
        uint o0 = csrb[start + j];
        uint4 v0 = *(const uint4*)(Tb + (o0 + sub16));
        accp(v0, acc);
    }

#pragma unroll
    for (int i = 0; i < 4; i++) {
        acc[i].x += __shfl_xor(acc[i].x, 16);
        acc[i].y += __shfl_xor(acc[i].y, 16);
        acc[i].x += __shfl_xor(acc[i].x, 32);
        acc[i].y += __shfl_xor(acc[i].y, 32);
    }

    if (group == 0) {
        // self term (weight 1), then scale by dis[node], bias, relu
        uint4 sv = *(const uint4*)(Tb + (((uint)node << 8) + sub16));
        accp(sv, acc);
        float di = dis[node];
        int sub = lane & 15;
        float4 blo = ((const float4*)bias)[sub * 2];
        float4 bhi = ((const float4*)bias)[sub * 2 + 1];
        float bb[8] = {blo.x, blo.y, blo.z, blo.w, bhi.x, bhi.y, bhi.z, bhi.w};
        float r[8];
        float af[8] = {acc[0].x, acc[0].y, acc[1].x, acc[1].y,
                       acc[2].x, acc[2].y, acc[3].x, acc[3].y};
#pragma unroll
        for (int i = 0; i < 8; i++) r[i] = fmaxf(di * af[i] + bb[i], 0.f);
        ((uint4*)H)[(size_t)node * 16 + sub] = pack8(r);
    }
}

// ---------------- pool: chunked per-wave run-accumulation over sorted batch ----------------
__global__ __launch_bounds__(256) void pool_kernel(const ushort* __restrict__ H,
                                                   const int* __restrict__ batch,
                                                   const float* __restrict__ Wfc,
                                                   float* __restrict__ gsum) {
    int wave = threadIdx.x >> 6;
    int lane = threadIdx.x & 63;
    int wid = blockIdx.x * 4 + wave;
    const int nwaves = POOL_BLOCKS * 4;
    const int per = (N_NODES + nwaves - 1) / nwaves;
    int start = wid * per;
    int end = min(start + per, N_NODES);
    if (start >= end) return;

    const uint* H1 = (const uint*)H;
    float2 w = ((const float2*)Wfc)[lane];
    float2 acc = make_float2(0.f, 0.f);
    int gcur = batch[start];

    for (int node = start; node < end; ++node) {
        int g = batch[node];
        if (g != gcur) {
            float d = acc.x * w.x + acc.y * w.y;
#pragma unroll
            for (int off = 32; off > 0; off >>= 1) d += __shfl_down(d, off);
            if (lane == 0) atomicAdd(&gsum[gcur], d);
            acc = make_float2(0.f, 0.f);
            gcur = g;
        }
        uint v = H1[(size_t)node * 64 + lane];
        acc.x += bf2f((ushort)(v & 0xFFFF));
        acc.y += bf2f((ushort)(v >> 16));
    }
    float d = acc.x * w.x + acc.y * w.y;
#pragma unroll
    for (int off = 32; off > 0; off >>= 1) d += __shfl_down(d, off);
    if (lane == 0) atomicAdd(&gsum[gcur], d);
}

// ---------------- finalize ----------------
__global__ void finalize_kernel(const float* __restrict__ gsum, const int* __restrict__ batch,
                                const float* __restrict__ bfc, float* __restrict__ out) {
    int g = threadIdx.x;
    if (g >= N_GRAPHS) return;
    auto lb = [&](int key) {
        int lo = 0, hi = N_NODES;
        while (lo < hi) {
            int mid = (lo + hi) >> 1;
            if (batch[mid] < key) lo = mid + 1; else hi = mid;
        }
        return lo;
    };
    int a = lb(g), b = lb(g + 1);
    float cnt = (float)(b - a);
    out[g] = gsum[g] / fmaxf(cnt, 1.0f) + bfc[0];
}

// ---------------- launcher ----------------
extern "C" void kernel_launch(void* const* d_in, const int* in_sizes, int n_in,
                              void* d_out, int out_size, void* d_ws, size_t ws_size,
                              hipStream_t stream) {
    const float* x    = (const float*)d_in[0];
    const int*   eidx = (const int*)d_in[1];
    const int*   batch= (const int*)d_in[2];
    const float* W1   = (const float*)d_in[3];
    const float* b1   = (const float*)d_in[4];
    const float* W2   = (const float*)d_in[5];
    const float* b2   = (const float*)d_in[6];
    const float* Wfc  = (const float*)d_in[7];
    const float* bfc  = (const float*)d_in[8];
    float* out = (float*)d_out;

    const int* src = eidx;
    const int* dst = eidx + N_EDGES;

    size_t off = 0;
    char* base = (char*)d_ws;
    auto alloc = [&](size_t bytes) -> void* {
        void* p = base + off;
        off += (bytes + 255) & ~(size_t)255;
        return p;
    };
    // zeroed region first: bfill, gsum
    int*    bfill  = (int*)alloc(NBUCK * 4);
    float*  gsum   = (float*)alloc(N_GRAPHS * 4);
    size_t zero_bytes = off;
    ushort* A      = (ushort*)alloc((size_t)N_NODES * HID * 2);
    ushort* B      = (ushort*)alloc((size_t)N_NODES * HID * 2);
    int*    degi   = (int*)alloc(N_NODES * 4);
    int*    rowptr = (int*)alloc(N_NODES * 4);
    float*  dis    = (float*)alloc(N_NODES * 4);
    uint*   csrb   = (uint*)alloc((size_t)NBUCK * BCAP * 4);
    uint*   bucketed = (uint*)alloc((size_t)NBUCK * BCAP * 4);
    uint4*  WB1    = (uint4*)alloc(2048 * 16);
    uint4*  WB2    = (uint4*)alloc(2048 * 16);

    int zn = (int)(zero_bytes / 4);
    zero_kernel<<<(zn + 255) / 256, 256, 0, stream>>>((int*)base, zn);

    // bucketed CSR build (fixed-capacity, 2 passes total)
    bucket_scatter_kernel<<<NBLK_A, 256, 0, stream>>>(src, dst, bfill, bucketed);
    bucket_csr_kernel<<<NBUCK, 256, 0, stream>>>(bucketed, bfill, degi, rowptr, dis, csrb);

    // W fragment pre-pack (both layers)
    prep_wfrag2<<<16, 256, 0, stream>>>(W1, W2, WB1, WB2);

    int gemm_grid = (N_NODES + 127) / 128;
    int agg_grid  = (N_NODES + 3) / 4;

    // layer 1
    mgemm_kernel<true><<<gemm_grid, 256, 0, stream>>>(x, WB1, dis, A, N_NODES);
    aggregate_kernel<<<agg_grid, 256, 0, stream>>>(A, csrb, rowptr, degi, dis, b1, B);
    // layer 2
    mgemm_kernel<false><<<gemm_grid, 256, 0, stream>>>(B, WB2, dis, A, N_NODES);
    aggregate_kernel<<<agg_grid, 256, 0, stream>>>(A, csrb, rowptr, degi, dis, b2, B);

    // pool + fc
    pool_kernel<<<POOL_BLOCKS, 256, 0, stream>>>(B, batch, Wfc, gsum);
    finalize_kernel<<<1, 256, 0, stream>>>(gsum, batch, bfc, out);
}